// Round 1
// baseline (1854.782 us; speedup 1.0000x reference)
//
#include <hip/hip_runtime.h>

#define EMBED_DIM 64
#define NUM_GROUPS 10000

// Work decomposition: 16 chunks of 4 dims (float4) per row.
// Lane i of a 16-thread group handles dims [4i, 4i+4) of one row.

__global__ void accum_kernel(const int* __restrict__ keys,
                             const float* __restrict__ emb,
                             float* __restrict__ sums,
                             float* __restrict__ sqs,
                             float* __restrict__ counts,
                             int n_rows) {
    const long long total = (long long)n_rows * 16;
    const long long stride = (long long)gridDim.x * blockDim.x;
    for (long long idx = (long long)blockIdx.x * blockDim.x + threadIdx.x;
         idx < total; idx += stride) {
        const int row   = (int)(idx >> 4);
        const int chunk = (int)(idx & 15);
        const int key   = keys[row];
        const float4 v = *reinterpret_cast<const float4*>(
            emb + (size_t)row * EMBED_DIM + chunk * 4);
        float* sbase = sums + (size_t)key * EMBED_DIM + chunk * 4;
        float* qbase = sqs  + (size_t)key * EMBED_DIM + chunk * 4;
        atomicAdd(sbase + 0, v.x);
        atomicAdd(sbase + 1, v.y);
        atomicAdd(sbase + 2, v.z);
        atomicAdd(sbase + 3, v.w);
        atomicAdd(qbase + 0, v.x * v.x);
        atomicAdd(qbase + 1, v.y * v.y);
        atomicAdd(qbase + 2, v.z * v.z);
        atomicAdd(qbase + 3, v.w * v.w);
        if (chunk == 0) atomicAdd(counts + key, 1.0f);
    }
}

__global__ void finalize_kernel(float* __restrict__ sums,   // -> mean in place
                                float* __restrict__ sqs,    // -> var in place
                                const float* __restrict__ counts) {
    const int idx = blockIdx.x * blockDim.x + threadIdx.x;
    if (idx >= NUM_GROUPS * EMBED_DIM) return;
    const int g = idx >> 6;  // /EMBED_DIM
    const float denom = fmaxf(counts[g], 1.0f);
    const float inv = 1.0f / denom;
    const float m = sums[idx] * inv;
    const float v = sqs[idx] * inv - m * m;
    sums[idx] = m;
    sqs[idx] = v;
}

__global__ void gather_kernel(const int* __restrict__ keys,
                              const float* __restrict__ mean_g,
                              const float* __restrict__ var_g,
                              float* __restrict__ out,
                              int n_rows) {
    const long long total = (long long)n_rows * 16;
    const long long stride = (long long)gridDim.x * blockDim.x;
    const size_t var_off = (size_t)n_rows * EMBED_DIM;
    for (long long idx = (long long)blockIdx.x * blockDim.x + threadIdx.x;
         idx < total; idx += stride) {
        const int row   = (int)(idx >> 4);
        const int chunk = (int)(idx & 15);
        const int key   = keys[row];
        const size_t gi = (size_t)key * EMBED_DIM + chunk * 4;
        const size_t oi = (size_t)row * EMBED_DIM + chunk * 4;
        const float4 m = *reinterpret_cast<const float4*>(mean_g + gi);
        const float4 v = *reinterpret_cast<const float4*>(var_g + gi);
        *reinterpret_cast<float4*>(out + oi)           = m;
        *reinterpret_cast<float4*>(out + var_off + oi) = v;
    }
}

extern "C" void kernel_launch(void* const* d_in, const int* in_sizes, int n_in,
                              void* d_out, int out_size, void* d_ws, size_t ws_size,
                              hipStream_t stream) {
    const int* keys  = (const int*)d_in[0];
    const float* emb = (const float*)d_in[1];
    float* out = (float*)d_out;
    const int n_rows = in_sizes[0];

    // Workspace layout: sums [G*D], sqs [G*D], counts [G]  (all fp32)
    float* sums   = (float*)d_ws;
    float* sqs    = sums + (size_t)NUM_GROUPS * EMBED_DIM;
    float* counts = sqs  + (size_t)NUM_GROUPS * EMBED_DIM;
    const size_t ws_bytes = ((size_t)2 * NUM_GROUPS * EMBED_DIM + NUM_GROUPS) * sizeof(float);

    // d_ws is poisoned once and never re-poisoned: zero accumulators every call.
    hipMemsetAsync(d_ws, 0, ws_bytes, stream);

    const int block = 256;
    const long long total_items = (long long)n_rows * 16;
    int grid_acc = (int)((total_items + block - 1) / block);
    if (grid_acc > 8192) grid_acc = 8192;   // grid-stride; 32 waves/CU is plenty

    accum_kernel<<<grid_acc, block, 0, stream>>>(keys, emb, sums, sqs, counts, n_rows);

    const int fin_grid = (NUM_GROUPS * EMBED_DIM + block - 1) / block;
    finalize_kernel<<<fin_grid, block, 0, stream>>>(sums, sqs, counts);

    gather_kernel<<<grid_acc, block, 0, stream>>>(keys, sums, sqs, out, n_rows);
}

// Round 2
// 421.357 us; speedup vs baseline: 4.4019x; 4.4019x over previous
//
#include <hip/hip_runtime.h>

#define D 64
#define G 10000
#define SCAN_T 1024
#define PER_T 10   // SCAN_T * PER_T >= G

// ---------- K1: histogram of keys (int atomics, 40 KB L2-resident) ----------
__global__ void hist_kernel(const int* __restrict__ keys, int* __restrict__ counts, int n) {
    int stride = gridDim.x * blockDim.x;
    for (int i = blockIdx.x * blockDim.x + threadIdx.x; i < n; i += stride)
        atomicAdd(&counts[keys[i]], 1);
}

// ---------- K2: exclusive prefix sum over G counts (single block) ----------
__global__ void scan_kernel(const int* __restrict__ counts,
                            int* __restrict__ offs, int* __restrict__ cursor) {
    __shared__ int tsum[SCAN_T];
    const int t = threadIdx.x;
    const int base = t * PER_T;
    int local[PER_T];
    int s = 0;
    for (int j = 0; j < PER_T; ++j) {
        int idx = base + j;
        int c = (idx < G) ? counts[idx] : 0;
        local[j] = s;       // exclusive within this thread
        s += c;
    }
    tsum[t] = s;
    __syncthreads();
    // Hillis-Steele inclusive scan of per-thread sums
    for (int off = 1; off < SCAN_T; off <<= 1) {
        int v = (t >= off) ? tsum[t - off] : 0;
        __syncthreads();
        tsum[t] += v;
        __syncthreads();
    }
    const int prev = (t > 0) ? tsum[t - 1] : 0;
    for (int j = 0; j < PER_T; ++j) {
        int idx = base + j;
        if (idx < G) {
            int o = prev + local[j];
            offs[idx]   = o;
            cursor[idx] = o;
        }
    }
}

// ---------- K3: scatter row ids into per-group contiguous lists ----------
__global__ void scatter_kernel(const int* __restrict__ keys, int* __restrict__ cursor,
                               int* __restrict__ rowids, int n) {
    int stride = gridDim.x * blockDim.x;
    for (int i = blockIdx.x * blockDim.x + threadIdx.x; i < n; i += stride) {
        int k = keys[i];
        int pos = atomicAdd(&cursor[k], 1);
        rowids[pos] = i;
    }
}

// ---------- K4: one wave per group; register accumulation, no atomics ----------
__global__ void reduce_kernel(const int* __restrict__ rowids,
                              const int* __restrict__ offs,
                              const int* __restrict__ counts,
                              const float* __restrict__ emb,
                              float* __restrict__ mean_g,
                              float* __restrict__ var_g) {
    const int wave = (blockIdx.x * blockDim.x + threadIdx.x) >> 6;
    const int lane = threadIdx.x & 63;
    if (wave >= G) return;
    const int n = counts[wave];
    const int base = offs[wave];
    float s = 0.f, q = 0.f;
    for (int j0 = 0; j0 < n; j0 += 64) {
        const int m = min(64, n - j0);
        // 64 rowids loaded coalesced, broadcast one at a time via shfl;
        // each row read is a coalesced 256 B load across the wave.
        int rid = (j0 + lane < n) ? rowids[base + j0 + lane] : 0;
        for (int jj = 0; jj < m; ++jj) {
            int r = __shfl(rid, jj);
            float v = emb[(size_t)r * D + lane];
            s += v;
            q += v * v;
        }
    }
    const float denom = fmaxf((float)n, 1.0f);
    const float mean = s / denom;
    const float var  = q / denom - mean * mean;   // biased, matches tf.nn.moments
    mean_g[(size_t)wave * D + lane] = mean;
    var_g [(size_t)wave * D + lane] = var;
}

// ---------- K5: gather per-row mean/var (write-bound, 512 MB) ----------
__global__ void gather_kernel(const int* __restrict__ keys,
                              const float* __restrict__ mean_g,
                              const float* __restrict__ var_g,
                              float* __restrict__ out, int n_rows) {
    const long long total = (long long)n_rows * 16;
    const long long stride = (long long)gridDim.x * blockDim.x;
    const size_t var_off = (size_t)n_rows * D;
    for (long long idx = (long long)blockIdx.x * blockDim.x + threadIdx.x;
         idx < total; idx += stride) {
        const int row   = (int)(idx >> 4);
        const int chunk = (int)(idx & 15);
        const int key   = keys[row];
        const size_t gi = (size_t)key * D + chunk * 4;
        const size_t oi = (size_t)row * D + chunk * 4;
        const float4 m = *reinterpret_cast<const float4*>(mean_g + gi);
        const float4 v = *reinterpret_cast<const float4*>(var_g + gi);
        *reinterpret_cast<float4*>(out + oi)           = m;
        *reinterpret_cast<float4*>(out + var_off + oi) = v;
    }
}

extern "C" void kernel_launch(void* const* d_in, const int* in_sizes, int n_in,
                              void* d_out, int out_size, void* d_ws, size_t ws_size,
                              hipStream_t stream) {
    const int* keys  = (const int*)d_in[0];
    const float* emb = (const float*)d_in[1];
    float* out = (float*)d_out;
    const int n_rows = in_sizes[0];

    // Workspace layout (ints then floats; all offsets 16B-aligned at the float4 users):
    //   counts [G] | offs [G] | cursor [G] | rowids [N] | mean_g [G*D] | var_g [G*D]
    int* counts = (int*)d_ws;
    int* offs   = counts + G;
    int* cursor = offs + G;
    int* rowids = cursor + G;
    float* mean_g = (float*)(rowids + n_rows);
    float* var_g  = mean_g + (size_t)G * D;

    // counts must be zero each call (d_ws poisoned once, never re-poisoned).
    hipMemsetAsync(counts, 0, G * sizeof(int), stream);

    const int block = 256;
    int grid_n = (n_rows + block - 1) / block;
    if (grid_n > 4096) grid_n = 4096;

    hist_kernel<<<grid_n, block, 0, stream>>>(keys, counts, n_rows);
    scan_kernel<<<1, SCAN_T, 0, stream>>>(counts, offs, cursor);
    scatter_kernel<<<grid_n, block, 0, stream>>>(keys, cursor, rowids, n_rows);

    const int red_grid = (G * 64) / block;   // one 64-lane wave per group
    reduce_kernel<<<red_grid, block, 0, stream>>>(rowids, offs, counts, emb, mean_g, var_g);

    const long long total_items = (long long)n_rows * 16;
    int grid_gather = (int)((total_items + block - 1) / block);
    if (grid_gather > 8192) grid_gather = 8192;
    gather_kernel<<<grid_gather, block, 0, stream>>>(keys, mean_g, var_g, out, n_rows);
}

// Round 3
// 330.360 us; speedup vs baseline: 5.6144x; 1.2754x over previous
//
#include <hip/hip_runtime.h>

#define D 64
#define G 10000
#define SCAN_T 1024
#define PER_T 10   // SCAN_T * PER_T >= G

// ---------- K1: histogram of keys (int atomics, 40 KB L2-resident) ----------
__global__ void hist_kernel(const int* __restrict__ keys, int* __restrict__ counts, int n) {
    int stride = gridDim.x * blockDim.x;
    for (int i = blockIdx.x * blockDim.x + threadIdx.x; i < n; i += stride)
        atomicAdd(&counts[keys[i]], 1);
}

// ---------- K2: exclusive prefix sum over G counts (single block) ----------
__global__ void scan_kernel(const int* __restrict__ counts,
                            int* __restrict__ offs, int* __restrict__ cursor) {
    __shared__ int tsum[SCAN_T];
    const int t = threadIdx.x;
    const int base = t * PER_T;
    int local[PER_T];
    int s = 0;
    for (int j = 0; j < PER_T; ++j) {
        int idx = base + j;
        int c = (idx < G) ? counts[idx] : 0;
        local[j] = s;       // exclusive within this thread
        s += c;
    }
    tsum[t] = s;
    __syncthreads();
    for (int off = 1; off < SCAN_T; off <<= 1) {
        int v = (t >= off) ? tsum[t - off] : 0;
        __syncthreads();
        tsum[t] += v;
        __syncthreads();
    }
    const int prev = (t > 0) ? tsum[t - 1] : 0;
    for (int j = 0; j < PER_T; ++j) {
        int idx = base + j;
        if (idx < G) {
            int o = prev + local[j];
            offs[idx]   = o;
            cursor[idx] = o;
        }
    }
}

// ---------- K3: scatter row ids into per-group contiguous lists ----------
__global__ void scatter_kernel(const int* __restrict__ keys, int* __restrict__ cursor,
                               int* __restrict__ rowids, int n) {
    int stride = gridDim.x * blockDim.x;
    for (int i = blockIdx.x * blockDim.x + threadIdx.x; i < n; i += stride) {
        int pos = atomicAdd(&cursor[keys[i]], 1);
        rowids[pos] = i;
    }
}

// ---------- K4: one wave per group; float4 lanes, fused stat-scatter ----------
// Lane layout: lane l owns dims [(l&15)*4, (l&15)*4+4) of row-subgroup (l>>4).
// Each global load/store instruction covers 4 rows x 256 B = 1 KB.
__global__ void reduce_write_kernel(const int* __restrict__ rowids,
                                    const int* __restrict__ offs,
                                    const int* __restrict__ counts,
                                    const float* __restrict__ emb,
                                    float* __restrict__ out, int n_rows) {
    const int wave = (blockIdx.x * blockDim.x + threadIdx.x) >> 6;
    const int lane = threadIdx.x & 63;
    if (wave >= G) return;
    const int n = counts[wave];
    if (n == 0) return;                 // empty group: no rows to write
    const int base = offs[wave];
    const int sub   = lane >> 4;        // which of 4 rows this lane covers
    const int dbase = (lane & 15) << 2; // this lane's dim base

    float s[4] = {0.f, 0.f, 0.f, 0.f};
    float q[4] = {0.f, 0.f, 0.f, 0.f};

    for (int j0 = 0; j0 < n; j0 += 64) {
        const int m = min(64, n - j0);
        int rid = (lane < m) ? rowids[base + j0 + lane] : 0;
        const int iters = (m + 3) >> 2;
        for (int jj = 0; jj < iters; ++jj) {
            const int j = (jj << 2) + sub;      // row within this 64-chunk
            const int r = __shfl(rid, j);       // divergent-src bpermute: ok
            if (j < m) {
                const float4 v = *reinterpret_cast<const float4*>(
                    emb + (size_t)r * D + dbase);
                s[0] += v.x; s[1] += v.y; s[2] += v.z; s[3] += v.w;
                q[0] += v.x * v.x; q[1] += v.y * v.y;
                q[2] += v.z * v.z; q[3] += v.w * v.w;
            }
        }
    }
    // Combine the 4 row-subgroups: lanes sharing (l&15) hold partial sums.
#pragma unroll
    for (int k = 0; k < 4; ++k) {
        s[k] += __shfl_xor(s[k], 16);
        q[k] += __shfl_xor(q[k], 16);
        s[k] += __shfl_xor(s[k], 32);
        q[k] += __shfl_xor(q[k], 32);
    }
    const float inv = 1.0f / (float)n;
    float4 mean, var;
    mean.x = s[0] * inv; mean.y = s[1] * inv;
    mean.z = s[2] * inv; mean.w = s[3] * inv;
    var.x = q[0] * inv - mean.x * mean.x;
    var.y = q[1] * inv - mean.y * mean.y;
    var.z = q[2] * inv - mean.z * mean.z;
    var.w = q[3] * inv - mean.w * mean.w;   // biased, matches tf.nn.moments

    const size_t var_off = (size_t)n_rows * D;
    // Scatter mean/var back to every row of the group, 4 rows per iteration.
    for (int j0 = 0; j0 < n; j0 += 64) {
        const int m = min(64, n - j0);
        int rid = (lane < m) ? rowids[base + j0 + lane] : 0;
        const int iters = (m + 3) >> 2;
        for (int jj = 0; jj < iters; ++jj) {
            const int j = (jj << 2) + sub;
            const int r = __shfl(rid, j);
            if (j < m) {
                float* p = out + (size_t)r * D + dbase;
                *reinterpret_cast<float4*>(p)           = mean;
                *reinterpret_cast<float4*>(p + var_off) = var;
            }
        }
    }
}

extern "C" void kernel_launch(void* const* d_in, const int* in_sizes, int n_in,
                              void* d_out, int out_size, void* d_ws, size_t ws_size,
                              hipStream_t stream) {
    const int* keys  = (const int*)d_in[0];
    const float* emb = (const float*)d_in[1];
    float* out = (float*)d_out;
    const int n_rows = in_sizes[0];

    // Workspace: counts [G] | offs [G] | cursor [G] | rowids [N]   (~4.1 MB)
    int* counts = (int*)d_ws;
    int* offs   = counts + G;
    int* cursor = offs + G;
    int* rowids = cursor + G;

    // counts must be zero each call (d_ws poisoned once, never re-poisoned).
    hipMemsetAsync(counts, 0, G * sizeof(int), stream);

    const int block = 256;
    int grid_n = (n_rows + block - 1) / block;
    if (grid_n > 4096) grid_n = 4096;

    hist_kernel<<<grid_n, block, 0, stream>>>(keys, counts, n_rows);
    scan_kernel<<<1, SCAN_T, 0, stream>>>(counts, offs, cursor);
    scatter_kernel<<<grid_n, block, 0, stream>>>(keys, cursor, rowids, n_rows);

    const int red_grid = (G * 64) / block;   // one 64-lane wave per group
    reduce_write_kernel<<<red_grid, block, 0, stream>>>(rowids, offs, counts,
                                                        emb, out, n_rows);
}